// Round 2
// baseline (358.932 us; speedup 1.0000x reference)
//
#include <hip/hip_runtime.h>
#include <math.h>

#define NN 1024
#define BB 2
#define D 64
#define NHEAD 4
#define PH 16
#define LOG2E 1.4426950408889634f

template <int CTRL>
__device__ __forceinline__ float dpp_mov(float x) {
    int xi = __builtin_bit_cast(int, x);
    int r = __builtin_amdgcn_update_dpp(0, xi, CTRL, 0xF, 0xF, true);
    return __builtin_bit_cast(float, r);
}

// 16-lane row sum; valid in lane 15 of each row of 16.
__device__ __forceinline__ float dpp_rowsum16(float t) {
    t += dpp_mov<0x111>(t);
    t += dpp_mov<0x112>(t);
    t += dpp_mov<0x114>(t);
    t += dpp_mov<0x118>(t);
    return t;
}

// sum across a 4-lane quad via quad_perm butterfly; valid in ALL quad lanes.
__device__ __forceinline__ float quad_sum4(float t) {
    t += dpp_mov<0xB1>(t);   // quad_perm [1,0,3,2]
    t += dpp_mov<0x4E>(t);   // quad_perm [2,3,0,1]
    return t;
}

// --- Kernel 1: adjacency mask as tiled GEMM on RAW embedding rows --------
// norms are positive & finite, so (ne_i.ne_j != 0) <=> (emb_i.emb_j != 0).
#define MST 65
__global__ __launch_bounds__(256) void k_mask(const float* __restrict__ emb,
                                              unsigned char* __restrict__ mask) {
    __shared__ float As[64 * MST];
    __shared__ float Bs[64 * MST];
    int tid = threadIdx.x;
    int ib = (blockIdx.x & 15) << 6;
    int jb = (blockIdx.x >> 4) << 6;

    #pragma unroll
    for (int r = 0; r < 4; ++r) {
        int q = tid + (r << 8);
        int row = q >> 4, c4 = (q & 15) << 2;
        float4 a = *(const float4*)&emb[(ib + row) * D + c4];
        float4 b = *(const float4*)&emb[(jb + row) * D + c4];
        As[row * MST + c4 + 0] = a.x; As[row * MST + c4 + 1] = a.y;
        As[row * MST + c4 + 2] = a.z; As[row * MST + c4 + 3] = a.w;
        Bs[row * MST + c4 + 0] = b.x; Bs[row * MST + c4 + 1] = b.y;
        Bs[row * MST + c4 + 2] = b.z; Bs[row * MST + c4 + 3] = b.w;
    }
    __syncthreads();

    int i0 = (tid >> 4) << 2;
    int j0 = (tid & 15) << 2;
    float acc[4][4] = {};
    #pragma unroll 8
    for (int k = 0; k < 64; ++k) {
        float a0 = As[(i0 + 0) * MST + k];
        float a1 = As[(i0 + 1) * MST + k];
        float a2 = As[(i0 + 2) * MST + k];
        float a3 = As[(i0 + 3) * MST + k];
        float b0 = Bs[(j0 + 0) * MST + k];
        float b1 = Bs[(j0 + 1) * MST + k];
        float b2 = Bs[(j0 + 2) * MST + k];
        float b3 = Bs[(j0 + 3) * MST + k];
        acc[0][0] = fmaf(a0, b0, acc[0][0]); acc[0][1] = fmaf(a0, b1, acc[0][1]);
        acc[0][2] = fmaf(a0, b2, acc[0][2]); acc[0][3] = fmaf(a0, b3, acc[0][3]);
        acc[1][0] = fmaf(a1, b0, acc[1][0]); acc[1][1] = fmaf(a1, b1, acc[1][1]);
        acc[1][2] = fmaf(a1, b2, acc[1][2]); acc[1][3] = fmaf(a1, b3, acc[1][3]);
        acc[2][0] = fmaf(a2, b0, acc[2][0]); acc[2][1] = fmaf(a2, b1, acc[2][1]);
        acc[2][2] = fmaf(a2, b2, acc[2][2]); acc[2][3] = fmaf(a2, b3, acc[2][3]);
        acc[3][0] = fmaf(a3, b0, acc[3][0]); acc[3][1] = fmaf(a3, b1, acc[3][1]);
        acc[3][2] = fmaf(a3, b2, acc[3][2]); acc[3][3] = fmaf(a3, b3, acc[3][3]);
    }
    #pragma unroll
    for (int r = 0; r < 4; ++r) {
        int gi = ib + i0 + r;
        uchar4 m;
        m.x = (acc[r][0] != 0.f || gi == jb + j0 + 0) ? 1 : 0;
        m.y = (acc[r][1] != 0.f || gi == jb + j0 + 1) ? 1 : 0;
        m.z = (acc[r][2] != 0.f || gi == jb + j0 + 2) ? 1 : 0;
        m.w = (acc[r][3] != 0.f || gi == jb + j0 + 3) ? 1 : 0;
        *(uchar4*)&mask[gi * NN + jb + j0] = m;
    }
}

// --- Kernel 2: dual GEMM + alE tail --------------------------------------
// xl = A@Wl, xr = A@Wr; alE[r][h] = 0.6*log2(e)*sum_p att[h,p]*xl[r,h,p]
__global__ __launch_bounds__(256) void k_gemm2(const float* __restrict__ A,
                                               const float* __restrict__ Wl,
                                               const float* __restrict__ Wr,
                                               const float* __restrict__ att,
                                               float* __restrict__ xl,
                                               float* __restrict__ xr,
                                               float* __restrict__ alE) {
    __shared__ float wl[64 * 64];
    __shared__ float wr[64 * 64];
    int tid = threadIdx.x;
    for (int t = tid; t < 4096; t += 256) { wl[t] = Wl[t]; wr[t] = Wr[t]; }
    __syncthreads();
    int r = blockIdx.x * 4 + (tid >> 6);
    int c = tid & 63;
    float av = att[c];
    const float* arow = A + r * 64;
    float accl = 0.f, accr = 0.f;
    #pragma unroll
    for (int p = 0; p < 64; ++p) {
        float a = arow[p];
        accl = fmaf(a, wl[p * 64 + c], accl);
        accr = fmaf(a, wr[p * 64 + c], accr);
    }
    xl[r * 64 + c] = accl;
    xr[r * 64 + c] = accr;
    float t = dpp_rowsum16(accl * av);
    if ((c & 15) == 15) alE[(r << 2) | (c >> 4)] = 0.6f * LOG2E * t;
}

// --- Kernel 3: fused flash GATv2, quad-cooperative loads -----------------
// lane = 4*jl + h; quad (jl) shares row j = wave*256 + jl*16 + s.
// Lane owns p-set {q*16 + 4h + r} (4 elems of each head-slice q).
// e'[j,q] = quadsum(sum_r at'[q][r]*|xr+xv|) + arE[i][q] + alE[j][q]
// with at' = 0.4*log2e*att (permuted), arE = 1.5*quadsum(at'.xr).
// 4 i-rows per block: halves L2 xl traffic, amortizes xv loads 4x.
// __launch_bounds__(256,2): 256-VGPR budget -> no spills, deep prefetch.
template <bool RELU>
__global__ __launch_bounds__(256, 2) void k_attn(
    const float* __restrict__ xl, const float* __restrict__ xr,
    const float* __restrict__ att, const float* __restrict__ alE,
    const float* __restrict__ bias, const unsigned char* __restrict__ mask,
    float* __restrict__ out)
{
    __shared__ float Opart[4][4][4][64];   // [ii][wave][jlgrp][p]
    __shared__ float Lpart[4][4][4][NHEAD];

    int tid = threadIdx.x;
    int wave = tid >> 6, lane = tid & 63;
    int h = lane & 3, jl = lane >> 2;
    int b = blockIdx.x >> 8;
    int i0 = (blockIdx.x & 255) << 2;
    int j0 = (wave << 8) + (jl << 4);

    const float* xlb = xl + (b << 16);

    // permuted persistent fragments: slot q*4+r  <->  p = q*16 + 4h + r
    float at[16];
    float xrf[4][16];
    {
        const float* ap = att + (h << 2);
        #pragma unroll
        for (int q = 0; q < 4; ++q)
            *(float4*)&at[q << 2] = *(const float4*)(ap + (q << 4));
        #pragma unroll
        for (int p = 0; p < 16; ++p) at[p] *= 0.4f * LOG2E;
        #pragma unroll
        for (int rw = 0; rw < 4; ++rw) {
            const float* rp = xr + (((b << 10) + i0 + rw) << 6) + (h << 2);
            #pragma unroll
            for (int q = 0; q < 4; ++q)
                *(float4*)&xrf[rw][q << 2] = *(const float4*)(rp + (q << 4));
        }
    }
    // arE[i][q] for all q, in every lane (init-time quad butterfly)
    float arq[4][4];
    #pragma unroll
    for (int rw = 0; rw < 4; ++rw) {
        #pragma unroll
        for (int q = 0; q < 4; ++q) {
            float p0 = 0.f;
            #pragma unroll
            for (int r = 0; r < 4; ++r)
                p0 = fmaf(at[(q << 2) + r], xrf[rw][(q << 2) + r], p0);
            arq[rw][q] = 1.5f * quad_sum4(p0);
        }
    }

    // pack this lane's 16 mask bytes into 16 bits, for rows i0..i0+3
    unsigned mb[4];
    #pragma unroll
    for (int rw = 0; rw < 4; ++rw) {
        const unsigned* mp = (const unsigned*)(mask + (i0 + rw) * NN + j0);
        unsigned acc = 0;
        #pragma unroll
        for (int q = 0; q < 4; ++q) {
            unsigned w = mp[q];
            acc |= ((((w >> 0) & 1) | ((w >> 7) & 2) | ((w >> 14) & 4) | ((w >> 21) & 8)) << (q << 2));
        }
        mb[rw] = acc;
    }

    float O[4][16];
    float lq[4][4];
    #pragma unroll
    for (int rw = 0; rw < 4; ++rw) {
        #pragma unroll
        for (int p = 0; p < 16; ++p) O[rw][p] = 0.f;
        #pragma unroll
        for (int q = 0; q < 4; ++q) lq[rw][q] = 0.f;
    }

    const float* xrow = xlb + (j0 << 6) + (h << 2);
    const float* alp  = alE + (b << 12) + (j0 << 2);

    auto loadt = [&](float (&xv)[16], float (&alr)[4], int s) {
        const float* rp = xrow + (s << 6);
        *(float4*)&xv[0]  = *(const float4*)(rp);
        *(float4*)&xv[4]  = *(const float4*)(rp + 16);
        *(float4*)&xv[8]  = *(const float4*)(rp + 32);
        *(float4*)&xv[12] = *(const float4*)(rp + 48);
        *(float4*)alr = *(const float4*)(alp + (s << 2));
    };

    auto compute = [&](const float (&xv)[16], const float (&alr)[4], int s) {
        #pragma unroll
        for (int q = 0; q < 4; ++q) {
            float pp[4];
            #pragma unroll
            for (int rw = 0; rw < 4; ++rw) {
                float t = 0.f;
                #pragma unroll
                for (int r = 0; r < 4; ++r)
                    t = fmaf(at[(q << 2) + r],
                             __builtin_fabsf(xrf[rw][(q << 2) + r] + xv[(q << 2) + r]), t);
                pp[rw] = t;
            }
            #pragma unroll
            for (int rw = 0; rw < 4; ++rw) {
                float e = quad_sum4(pp[rw]) + (arq[rw][q] + alr[q]);
                float pe = ((mb[rw] >> s) & 1) ? __builtin_amdgcn_exp2f(e) : 0.f;
                lq[rw][q] += pe;
                #pragma unroll
                for (int r = 0; r < 4; ++r)
                    O[rw][(q << 2) + r] = fmaf(pe, xv[(q << 2) + r], O[rw][(q << 2) + r]);
            }
        }
    };

    // explicit ping-pong software pipeline: loads for s+1 issued a full
    // compute-phase (~600 cyc) ahead of use -> L2 latency hidden by ILP.
    float xvA[16], alrA[4], xvB[16], alrB[4];
    loadt(xvA, alrA, 0);
    #pragma unroll
    for (int s = 0; s < 16; s += 2) {
        loadt(xvB, alrB, s + 1);
        compute(xvA, alrA, s);
        if (s + 2 < 16) loadt(xvA, alrA, s + 2);
        compute(xvB, alrB, s + 1);
    }

    // reduce over the 4 jl's within each 16-lane DPP row (stride-4 lanes)
    #pragma unroll
    for (int rw = 0; rw < 4; ++rw) {
        #pragma unroll
        for (int p = 0; p < 16; ++p) {
            O[rw][p] += dpp_mov<0x114>(O[rw][p]);
            O[rw][p] += dpp_mov<0x118>(O[rw][p]);
        }
        #pragma unroll
        for (int q = 0; q < 4; ++q) {
            lq[rw][q] += dpp_mov<0x114>(lq[rw][q]);
            lq[rw][q] += dpp_mov<0x118>(lq[rw][q]);
        }
    }

    if ((lane & 15) >= 12) {             // lanes 12..15 of each DPP row
        int k = lane >> 4;               // jl-group
        #pragma unroll
        for (int rw = 0; rw < 4; ++rw) {
            #pragma unroll
            for (int q = 0; q < 4; ++q)
                *(float4*)&Opart[rw][wave][k][(q << 4) + (h << 2)] = *(const float4*)&O[rw][q << 2];
            if (h == 0) {
                #pragma unroll
                for (int q = 0; q < 4; ++q)
                    Lpart[rw][wave][k][q] = lq[rw][q];
            }
        }
    }
    __syncthreads();

    {
        int ii = tid >> 6, c = tid & 63;
        float o = 0.f, l = 0.f;
        #pragma unroll
        for (int w = 0; w < 4; ++w)
            #pragma unroll
            for (int k = 0; k < 4; ++k) {
                o += Opart[ii][w][k][c];
                l += Lpart[ii][w][k][c >> 4];
            }
        float res = o / l + bias[c];
        if (RELU) res = fmaxf(res, 0.f);
        out[((b << 10) + i0 + ii) * D + c] = res;
    }
}

extern "C" void kernel_launch(void* const* d_in, const int* in_sizes, int n_in,
                              void* d_out, int out_size, void* d_ws, size_t ws_size,
                              hipStream_t stream) {
    const float* x    = (const float*)d_in[0];
    const float* emb  = (const float*)d_in[1];
    const float* Wl1  = (const float*)d_in[2];
    const float* Wr1  = (const float*)d_in[3];
    const float* att1 = (const float*)d_in[4];
    const float* b1   = (const float*)d_in[5];
    const float* Wl2  = (const float*)d_in[6];
    const float* Wr2  = (const float*)d_in[7];
    const float* att2 = (const float*)d_in[8];
    const float* b2   = (const float*)d_in[9];
    float* out = (float*)d_out;

    unsigned char* mask = (unsigned char*)d_ws;                 // 1MB
    float* xl = (float*)(mask + NN * NN);                       // 512KB
    float* xr = xl + BB * NN * D;                               // 512KB
    float* hbuf = xr + BB * NN * D;                             // 512KB
    float* alE = hbuf + BB * NN * D;                            // 32KB

    k_mask<<<256, 256, 0, stream>>>(emb, mask);

    k_gemm2<<<BB * NN / 4, 256, 0, stream>>>(x, Wl1, Wr1, att1, xl, xr, alE);
    k_attn<true><<<BB * NN / 4, 256, 0, stream>>>(xl, xr, att1, alE, b1, mask, hbuf);

    k_gemm2<<<BB * NN / 4, 256, 0, stream>>>(hbuf, Wl2, Wr2, att2, xl, xr, alE);
    k_attn<false><<<BB * NN / 4, 256, 0, stream>>>(xl, xr, att2, alE, b2, mask, out);
}

// Round 3
// 342.909 us; speedup vs baseline: 1.0467x; 1.0467x over previous
//
#include <hip/hip_runtime.h>
#include <math.h>

#define NN 1024
#define BB 2
#define D 64
#define NHEAD 4
#define PH 16
#define LOG2E 1.4426950408889634f

template <int CTRL>
__device__ __forceinline__ float dpp_mov(float x) {
    int xi = __builtin_bit_cast(int, x);
    int r = __builtin_amdgcn_update_dpp(0, xi, CTRL, 0xF, 0xF, true);
    return __builtin_bit_cast(float, r);
}

// 16-lane row sum; valid in lane 15 of each row of 16.
__device__ __forceinline__ float dpp_rowsum16(float t) {
    t += dpp_mov<0x111>(t);
    t += dpp_mov<0x112>(t);
    t += dpp_mov<0x114>(t);
    t += dpp_mov<0x118>(t);
    return t;
}

// sum across a 4-lane quad via quad_perm butterfly; valid in ALL quad lanes.
__device__ __forceinline__ float quad_sum4(float t) {
    t += dpp_mov<0xB1>(t);   // quad_perm [1,0,3,2]
    t += dpp_mov<0x4E>(t);   // quad_perm [2,3,0,1]
    return t;
}

// --- Kernel 1: adjacency mask as tiled GEMM on RAW embedding rows --------
// norms are positive & finite, so (ne_i.ne_j != 0) <=> (emb_i.emb_j != 0).
#define MST 65
__global__ __launch_bounds__(256) void k_mask(const float* __restrict__ emb,
                                              unsigned char* __restrict__ mask) {
    __shared__ float As[64 * MST];
    __shared__ float Bs[64 * MST];
    int tid = threadIdx.x;
    int ib = (blockIdx.x & 15) << 6;
    int jb = (blockIdx.x >> 4) << 6;

    #pragma unroll
    for (int r = 0; r < 4; ++r) {
        int q = tid + (r << 8);
        int row = q >> 4, c4 = (q & 15) << 2;
        float4 a = *(const float4*)&emb[(ib + row) * D + c4];
        float4 b = *(const float4*)&emb[(jb + row) * D + c4];
        As[row * MST + c4 + 0] = a.x; As[row * MST + c4 + 1] = a.y;
        As[row * MST + c4 + 2] = a.z; As[row * MST + c4 + 3] = a.w;
        Bs[row * MST + c4 + 0] = b.x; Bs[row * MST + c4 + 1] = b.y;
        Bs[row * MST + c4 + 2] = b.z; Bs[row * MST + c4 + 3] = b.w;
    }
    __syncthreads();

    int i0 = (tid >> 4) << 2;
    int j0 = (tid & 15) << 2;
    float acc[4][4] = {};
    #pragma unroll 8
    for (int k = 0; k < 64; ++k) {
        float a0 = As[(i0 + 0) * MST + k];
        float a1 = As[(i0 + 1) * MST + k];
        float a2 = As[(i0 + 2) * MST + k];
        float a3 = As[(i0 + 3) * MST + k];
        float b0 = Bs[(j0 + 0) * MST + k];
        float b1 = Bs[(j0 + 1) * MST + k];
        float b2 = Bs[(j0 + 2) * MST + k];
        float b3 = Bs[(j0 + 3) * MST + k];
        acc[0][0] = fmaf(a0, b0, acc[0][0]); acc[0][1] = fmaf(a0, b1, acc[0][1]);
        acc[0][2] = fmaf(a0, b2, acc[0][2]); acc[0][3] = fmaf(a0, b3, acc[0][3]);
        acc[1][0] = fmaf(a1, b0, acc[1][0]); acc[1][1] = fmaf(a1, b1, acc[1][1]);
        acc[1][2] = fmaf(a1, b2, acc[1][2]); acc[1][3] = fmaf(a1, b3, acc[1][3]);
        acc[2][0] = fmaf(a2, b0, acc[2][0]); acc[2][1] = fmaf(a2, b1, acc[2][1]);
        acc[2][2] = fmaf(a2, b2, acc[2][2]); acc[2][3] = fmaf(a2, b3, acc[2][3]);
        acc[3][0] = fmaf(a3, b0, acc[3][0]); acc[3][1] = fmaf(a3, b1, acc[3][1]);
        acc[3][2] = fmaf(a3, b2, acc[3][2]); acc[3][3] = fmaf(a3, b3, acc[3][3]);
    }
    #pragma unroll
    for (int r = 0; r < 4; ++r) {
        int gi = ib + i0 + r;
        uchar4 m;
        m.x = (acc[r][0] != 0.f || gi == jb + j0 + 0) ? 1 : 0;
        m.y = (acc[r][1] != 0.f || gi == jb + j0 + 1) ? 1 : 0;
        m.z = (acc[r][2] != 0.f || gi == jb + j0 + 2) ? 1 : 0;
        m.w = (acc[r][3] != 0.f || gi == jb + j0 + 3) ? 1 : 0;
        *(uchar4*)&mask[gi * NN + jb + j0] = m;
    }
}

// --- Kernel 2: dual GEMM + alE tail --------------------------------------
// xl = A@Wl, xr = A@Wr; alE[r][h] = 0.6*log2(e)*sum_p att[h,p]*xl[r,h,p]
__global__ __launch_bounds__(256) void k_gemm2(const float* __restrict__ A,
                                               const float* __restrict__ Wl,
                                               const float* __restrict__ Wr,
                                               const float* __restrict__ att,
                                               float* __restrict__ xl,
                                               float* __restrict__ xr,
                                               float* __restrict__ alE) {
    __shared__ float wl[64 * 64];
    __shared__ float wr[64 * 64];
    int tid = threadIdx.x;
    for (int t = tid; t < 4096; t += 256) { wl[t] = Wl[t]; wr[t] = Wr[t]; }
    __syncthreads();
    int r = blockIdx.x * 4 + (tid >> 6);
    int c = tid & 63;
    float av = att[c];
    const float* arow = A + r * 64;
    float accl = 0.f, accr = 0.f;
    #pragma unroll
    for (int p = 0; p < 64; ++p) {
        float a = arow[p];
        accl = fmaf(a, wl[p * 64 + c], accl);
        accr = fmaf(a, wr[p * 64 + c], accr);
    }
    xl[r * 64 + c] = accl;
    xr[r * 64 + c] = accr;
    float t = dpp_rowsum16(accl * av);
    if ((c & 15) == 15) alE[(r << 2) | (c >> 4)] = 0.6f * LOG2E * t;
}

// --- Kernel 3: fused flash GATv2, quad-cooperative loads -----------------
// lane = 4*jl + h; quad (jl) shares row j = wave*256 + jl*16 + s.
// Lane owns p-set {q*16 + 4h + r} (4 elems of each head-slice q).
// e'[j,q] = quadsum(sum_r at'[q][r]*|xr+xv|) + arE[i][q] + alE[j][q]
// with at' = 0.4*log2e*att (permuted), arE = 1.5*quadsum(at'.xr).
// 4 i-rows per block; __launch_bounds__(256,2) -> 256-VGPR budget.
// NO lambdas / NO reference-array params: round-2 showed hipcc fails SROA
// on them (arrays -> scratch, 187MB/dispatch scratch writes, 147us).
// All pipeline state is named float4 registers; all indices compile-time.

#define LOADT(X0, X1, X2, X3, AL, s) do {                        \
    const float* rp_ = xrow + ((s) << 6);                        \
    X0 = *(const float4*)(rp_);                                  \
    X1 = *(const float4*)(rp_ + 16);                             \
    X2 = *(const float4*)(rp_ + 32);                             \
    X3 = *(const float4*)(rp_ + 48);                             \
    AL = *(const float4*)(alp + ((s) << 2));                     \
} while (0)

#define CQ(q, XV, ALQ, s) do {                                                     \
    float pp0, pp1, pp2, pp3;                                                      \
    pp0 = fmaf(at[(q<<2)+0], __builtin_fabsf(xrf[0][(q<<2)+0] + XV.x), 0.f);       \
    pp0 = fmaf(at[(q<<2)+1], __builtin_fabsf(xrf[0][(q<<2)+1] + XV.y), pp0);       \
    pp0 = fmaf(at[(q<<2)+2], __builtin_fabsf(xrf[0][(q<<2)+2] + XV.z), pp0);       \
    pp0 = fmaf(at[(q<<2)+3], __builtin_fabsf(xrf[0][(q<<2)+3] + XV.w), pp0);       \
    pp1 = fmaf(at[(q<<2)+0], __builtin_fabsf(xrf[1][(q<<2)+0] + XV.x), 0.f);       \
    pp1 = fmaf(at[(q<<2)+1], __builtin_fabsf(xrf[1][(q<<2)+1] + XV.y), pp1);       \
    pp1 = fmaf(at[(q<<2)+2], __builtin_fabsf(xrf[1][(q<<2)+2] + XV.z), pp1);       \
    pp1 = fmaf(at[(q<<2)+3], __builtin_fabsf(xrf[1][(q<<2)+3] + XV.w), pp1);       \
    pp2 = fmaf(at[(q<<2)+0], __builtin_fabsf(xrf[2][(q<<2)+0] + XV.x), 0.f);       \
    pp2 = fmaf(at[(q<<2)+1], __builtin_fabsf(xrf[2][(q<<2)+1] + XV.y), pp2);       \
    pp2 = fmaf(at[(q<<2)+2], __builtin_fabsf(xrf[2][(q<<2)+2] + XV.z), pp2);       \
    pp2 = fmaf(at[(q<<2)+3], __builtin_fabsf(xrf[2][(q<<2)+3] + XV.w), pp2);       \
    pp3 = fmaf(at[(q<<2)+0], __builtin_fabsf(xrf[3][(q<<2)+0] + XV.x), 0.f);       \
    pp3 = fmaf(at[(q<<2)+1], __builtin_fabsf(xrf[3][(q<<2)+1] + XV.y), pp3);       \
    pp3 = fmaf(at[(q<<2)+2], __builtin_fabsf(xrf[3][(q<<2)+2] + XV.z), pp3);       \
    pp3 = fmaf(at[(q<<2)+3], __builtin_fabsf(xrf[3][(q<<2)+3] + XV.w), pp3);       \
    float e0 = quad_sum4(pp0) + (arq[0][q] + ALQ);                                 \
    float e1 = quad_sum4(pp1) + (arq[1][q] + ALQ);                                 \
    float e2 = quad_sum4(pp2) + (arq[2][q] + ALQ);                                 \
    float e3 = quad_sum4(pp3) + (arq[3][q] + ALQ);                                 \
    float pe0 = ((mb[0] >> (s)) & 1) ? __builtin_amdgcn_exp2f(e0) : 0.f;           \
    float pe1 = ((mb[1] >> (s)) & 1) ? __builtin_amdgcn_exp2f(e1) : 0.f;           \
    float pe2 = ((mb[2] >> (s)) & 1) ? __builtin_amdgcn_exp2f(e2) : 0.f;           \
    float pe3 = ((mb[3] >> (s)) & 1) ? __builtin_amdgcn_exp2f(e3) : 0.f;           \
    lq[0][q] += pe0; lq[1][q] += pe1; lq[2][q] += pe2; lq[3][q] += pe3;            \
    O[0][(q<<2)+0] = fmaf(pe0, XV.x, O[0][(q<<2)+0]);                              \
    O[0][(q<<2)+1] = fmaf(pe0, XV.y, O[0][(q<<2)+1]);                              \
    O[0][(q<<2)+2] = fmaf(pe0, XV.z, O[0][(q<<2)+2]);                              \
    O[0][(q<<2)+3] = fmaf(pe0, XV.w, O[0][(q<<2)+3]);                              \
    O[1][(q<<2)+0] = fmaf(pe1, XV.x, O[1][(q<<2)+0]);                              \
    O[1][(q<<2)+1] = fmaf(pe1, XV.y, O[1][(q<<2)+1]);                              \
    O[1][(q<<2)+2] = fmaf(pe1, XV.z, O[1][(q<<2)+2]);                              \
    O[1][(q<<2)+3] = fmaf(pe1, XV.w, O[1][(q<<2)+3]);                              \
    O[2][(q<<2)+0] = fmaf(pe2, XV.x, O[2][(q<<2)+0]);                              \
    O[2][(q<<2)+1] = fmaf(pe2, XV.y, O[2][(q<<2)+1]);                              \
    O[2][(q<<2)+2] = fmaf(pe2, XV.z, O[2][(q<<2)+2]);                              \
    O[2][(q<<2)+3] = fmaf(pe2, XV.w, O[2][(q<<2)+3]);                              \
    O[3][(q<<2)+0] = fmaf(pe3, XV.x, O[3][(q<<2)+0]);                              \
    O[3][(q<<2)+1] = fmaf(pe3, XV.y, O[3][(q<<2)+1]);                              \
    O[3][(q<<2)+2] = fmaf(pe3, XV.z, O[3][(q<<2)+2]);                              \
    O[3][(q<<2)+3] = fmaf(pe3, XV.w, O[3][(q<<2)+3]);                              \
} while (0)

#define COMPUTE(X0, X1, X2, X3, AL, s) do {                      \
    CQ(0, X0, AL.x, s);                                          \
    CQ(1, X1, AL.y, s);                                          \
    CQ(2, X2, AL.z, s);                                          \
    CQ(3, X3, AL.w, s);                                          \
} while (0)

template <bool RELU>
__global__ __launch_bounds__(256, 2) void k_attn(
    const float* __restrict__ xl, const float* __restrict__ xr,
    const float* __restrict__ att, const float* __restrict__ alE,
    const float* __restrict__ bias, const unsigned char* __restrict__ mask,
    float* __restrict__ out)
{
    __shared__ float Opart[4][4][4][64];   // [ii][wave][jlgrp][p]
    __shared__ float Lpart[4][4][4][NHEAD];

    int tid = threadIdx.x;
    int wave = tid >> 6, lane = tid & 63;
    int h = lane & 3, jl = lane >> 2;
    int b = blockIdx.x >> 8;
    int i0 = (blockIdx.x & 255) << 2;
    int j0 = (wave << 8) + (jl << 4);

    const float* xlb = xl + (b << 16);

    // permuted persistent fragments: slot q*4+r  <->  p = q*16 + 4h + r
    float at[16];
    float xrf[4][16];
    {
        const float* ap = att + (h << 2);
        #pragma unroll
        for (int q = 0; q < 4; ++q)
            *(float4*)&at[q << 2] = *(const float4*)(ap + (q << 4));
        #pragma unroll
        for (int p = 0; p < 16; ++p) at[p] *= 0.4f * LOG2E;
        #pragma unroll
        for (int rw = 0; rw < 4; ++rw) {
            const float* rp = xr + (((b << 10) + i0 + rw) << 6) + (h << 2);
            #pragma unroll
            for (int q = 0; q < 4; ++q)
                *(float4*)&xrf[rw][q << 2] = *(const float4*)(rp + (q << 4));
        }
    }
    // arE[i][q] for all q, in every lane (init-time quad butterfly)
    float arq[4][4];
    #pragma unroll
    for (int rw = 0; rw < 4; ++rw) {
        #pragma unroll
        for (int q = 0; q < 4; ++q) {
            float p0 = 0.f;
            #pragma unroll
            for (int r = 0; r < 4; ++r)
                p0 = fmaf(at[(q << 2) + r], xrf[rw][(q << 2) + r], p0);
            arq[rw][q] = 1.5f * quad_sum4(p0);
        }
    }

    // pack this lane's 16 mask bytes into 16 bits, for rows i0..i0+3
    unsigned mb[4];
    #pragma unroll
    for (int rw = 0; rw < 4; ++rw) {
        const unsigned* mp = (const unsigned*)(mask + (i0 + rw) * NN + j0);
        unsigned acc = 0;
        #pragma unroll
        for (int q = 0; q < 4; ++q) {
            unsigned w = mp[q];
            acc |= ((((w >> 0) & 1) | ((w >> 7) & 2) | ((w >> 14) & 4) | ((w >> 21) & 8)) << (q << 2));
        }
        mb[rw] = acc;
    }

    float O[4][16];
    float lq[4][4];
    #pragma unroll
    for (int rw = 0; rw < 4; ++rw) {
        #pragma unroll
        for (int p = 0; p < 16; ++p) O[rw][p] = 0.f;
        #pragma unroll
        for (int q = 0; q < 4; ++q) lq[rw][q] = 0.f;
    }

    const float* xrow = xlb + (j0 << 6) + (h << 2);
    const float* alp  = alE + (b << 12) + (j0 << 2);

    // explicit ping-pong software pipeline on named float4 registers:
    // loads for s+1 issued a full compute-phase (~700 cyc) ahead of use.
    float4 xvA0, xvA1, xvA2, xvA3, alrA;
    float4 xvB0, xvB1, xvB2, xvB3, alrB;
    LOADT(xvA0, xvA1, xvA2, xvA3, alrA, 0);
    #pragma unroll
    for (int s = 0; s < 16; s += 2) {
        LOADT(xvB0, xvB1, xvB2, xvB3, alrB, s + 1);
        COMPUTE(xvA0, xvA1, xvA2, xvA3, alrA, s);
        if (s + 2 < 16) LOADT(xvA0, xvA1, xvA2, xvA3, alrA, s + 2);
        COMPUTE(xvB0, xvB1, xvB2, xvB3, alrB, s + 1);
    }

    // reduce over the 4 jl's within each 16-lane DPP row (stride-4 lanes)
    #pragma unroll
    for (int rw = 0; rw < 4; ++rw) {
        #pragma unroll
        for (int p = 0; p < 16; ++p) {
            O[rw][p] += dpp_mov<0x114>(O[rw][p]);
            O[rw][p] += dpp_mov<0x118>(O[rw][p]);
        }
        #pragma unroll
        for (int q = 0; q < 4; ++q) {
            lq[rw][q] += dpp_mov<0x114>(lq[rw][q]);
            lq[rw][q] += dpp_mov<0x118>(lq[rw][q]);
        }
    }

    if ((lane & 15) >= 12) {             // lanes 12..15 of each DPP row
        int k = lane >> 4;               // jl-group
        #pragma unroll
        for (int rw = 0; rw < 4; ++rw) {
            #pragma unroll
            for (int q = 0; q < 4; ++q)
                *(float4*)&Opart[rw][wave][k][(q << 4) + (h << 2)] = *(const float4*)&O[rw][q << 2];
            if (h == 0) {
                #pragma unroll
                for (int q = 0; q < 4; ++q)
                    Lpart[rw][wave][k][q] = lq[rw][q];
            }
        }
    }
    __syncthreads();

    {
        int ii = tid >> 6, c = tid & 63;
        float o = 0.f, l = 0.f;
        #pragma unroll
        for (int w = 0; w < 4; ++w)
            #pragma unroll
            for (int k = 0; k < 4; ++k) {
                o += Opart[ii][w][k][c];
                l += Lpart[ii][w][k][c >> 4];
            }
        float res = o / l + bias[c];
        if (RELU) res = fmaxf(res, 0.f);
        out[((b << 10) + i0 + ii) * D + c] = res;
    }
}

extern "C" void kernel_launch(void* const* d_in, const int* in_sizes, int n_in,
                              void* d_out, int out_size, void* d_ws, size_t ws_size,
                              hipStream_t stream) {
    const float* x    = (const float*)d_in[0];
    const float* emb  = (const float*)d_in[1];
    const float* Wl1  = (const float*)d_in[2];
    const float* Wr1  = (const float*)d_in[3];
    const float* att1 = (const float*)d_in[4];
    const float* b1   = (const float*)d_in[5];
    const float* Wl2  = (const float*)d_in[6];
    const float* Wr2  = (const float*)d_in[7];
    const float* att2 = (const float*)d_in[8];
    const float* b2   = (const float*)d_in[9];
    float* out = (float*)d_out;

    unsigned char* mask = (unsigned char*)d_ws;                 // 1MB
    float* xl = (float*)(mask + NN * NN);                       // 512KB
    float* xr = xl + BB * NN * D;                               // 512KB
    float* hbuf = xr + BB * NN * D;                             // 512KB
    float* alE = hbuf + BB * NN * D;                            // 32KB

    k_mask<<<256, 256, 0, stream>>>(emb, mask);

    k_gemm2<<<BB * NN / 4, 256, 0, stream>>>(x, Wl1, Wr1, att1, xl, xr, alE);
    k_attn<true><<<BB * NN / 4, 256, 0, stream>>>(xl, xr, att1, alE, b1, mask, hbuf);

    k_gemm2<<<BB * NN / 4, 256, 0, stream>>>(hbuf, Wl2, Wr2, att2, xl, xr, alE);
    k_attn<false><<<BB * NN / 4, 256, 0, stream>>>(xl, xr, att2, alE, b2, mask, out);
}

// Round 4
// 175.587 us; speedup vs baseline: 2.0442x; 1.9529x over previous
//
#include <hip/hip_runtime.h>
#include <math.h>

#define NN 1024
#define BB 2
#define D 64
#define NHEAD 4
#define PH 16
#define LOG2E 1.4426950408889634f

template <int CTRL>
__device__ __forceinline__ float dpp_mov(float x) {
    int xi = __builtin_bit_cast(int, x);
    int r = __builtin_amdgcn_update_dpp(0, xi, CTRL, 0xF, 0xF, true);
    return __builtin_bit_cast(float, r);
}

// 16-lane row sum; valid in lane 15 of each row of 16.
__device__ __forceinline__ float dpp_rowsum16(float t) {
    t += dpp_mov<0x111>(t);
    t += dpp_mov<0x112>(t);
    t += dpp_mov<0x114>(t);
    t += dpp_mov<0x118>(t);
    return t;
}

// sum across a 4-lane quad via quad_perm butterfly; valid in ALL quad lanes.
__device__ __forceinline__ float quad_sum4(float t) {
    t += dpp_mov<0xB1>(t);   // quad_perm [1,0,3,2]
    t += dpp_mov<0x4E>(t);   // quad_perm [2,3,0,1]
    return t;
}

// --- Kernel 1: adjacency mask as tiled GEMM on RAW embedding rows --------
// norms are positive & finite, so (ne_i.ne_j != 0) <=> (emb_i.emb_j != 0).
#define MST 65
__global__ __launch_bounds__(256) void k_mask(const float* __restrict__ emb,
                                              unsigned char* __restrict__ mask) {
    __shared__ float As[64 * MST];
    __shared__ float Bs[64 * MST];
    int tid = threadIdx.x;
    int ib = (blockIdx.x & 15) << 6;
    int jb = (blockIdx.x >> 4) << 6;

    #pragma unroll
    for (int r = 0; r < 4; ++r) {
        int q = tid + (r << 8);
        int row = q >> 4, c4 = (q & 15) << 2;
        float4 a = *(const float4*)&emb[(ib + row) * D + c4];
        float4 b = *(const float4*)&emb[(jb + row) * D + c4];
        As[row * MST + c4 + 0] = a.x; As[row * MST + c4 + 1] = a.y;
        As[row * MST + c4 + 2] = a.z; As[row * MST + c4 + 3] = a.w;
        Bs[row * MST + c4 + 0] = b.x; Bs[row * MST + c4 + 1] = b.y;
        Bs[row * MST + c4 + 2] = b.z; Bs[row * MST + c4 + 3] = b.w;
    }
    __syncthreads();

    int i0 = (tid >> 4) << 2;
    int j0 = (tid & 15) << 2;
    float acc[4][4] = {};
    #pragma unroll 8
    for (int k = 0; k < 64; ++k) {
        float a0 = As[(i0 + 0) * MST + k];
        float a1 = As[(i0 + 1) * MST + k];
        float a2 = As[(i0 + 2) * MST + k];
        float a3 = As[(i0 + 3) * MST + k];
        float b0 = Bs[(j0 + 0) * MST + k];
        float b1 = Bs[(j0 + 1) * MST + k];
        float b2 = Bs[(j0 + 2) * MST + k];
        float b3 = Bs[(j0 + 3) * MST + k];
        acc[0][0] = fmaf(a0, b0, acc[0][0]); acc[0][1] = fmaf(a0, b1, acc[0][1]);
        acc[0][2] = fmaf(a0, b2, acc[0][2]); acc[0][3] = fmaf(a0, b3, acc[0][3]);
        acc[1][0] = fmaf(a1, b0, acc[1][0]); acc[1][1] = fmaf(a1, b1, acc[1][1]);
        acc[1][2] = fmaf(a1, b2, acc[1][2]); acc[1][3] = fmaf(a1, b3, acc[1][3]);
        acc[2][0] = fmaf(a2, b0, acc[2][0]); acc[2][1] = fmaf(a2, b1, acc[2][1]);
        acc[2][2] = fmaf(a2, b2, acc[2][2]); acc[2][3] = fmaf(a2, b3, acc[2][3]);
        acc[3][0] = fmaf(a3, b0, acc[3][0]); acc[3][1] = fmaf(a3, b1, acc[3][1]);
        acc[3][2] = fmaf(a3, b2, acc[3][2]); acc[3][3] = fmaf(a3, b3, acc[3][3]);
    }
    #pragma unroll
    for (int r = 0; r < 4; ++r) {
        int gi = ib + i0 + r;
        uchar4 m;
        m.x = (acc[r][0] != 0.f || gi == jb + j0 + 0) ? 1 : 0;
        m.y = (acc[r][1] != 0.f || gi == jb + j0 + 1) ? 1 : 0;
        m.z = (acc[r][2] != 0.f || gi == jb + j0 + 2) ? 1 : 0;
        m.w = (acc[r][3] != 0.f || gi == jb + j0 + 3) ? 1 : 0;
        *(uchar4*)&mask[gi * NN + jb + j0] = m;
    }
}

// --- Kernel 2: dual GEMM + alE tail --------------------------------------
// xl = A@Wl, xr = A@Wr; alE[r][h] = 0.6*log2(e)*sum_p att[h,p]*xl[r,h,p]
__global__ __launch_bounds__(256) void k_gemm2(const float* __restrict__ A,
                                               const float* __restrict__ Wl,
                                               const float* __restrict__ Wr,
                                               const float* __restrict__ att,
                                               float* __restrict__ xl,
                                               float* __restrict__ xr,
                                               float* __restrict__ alE) {
    __shared__ float wl[64 * 64];
    __shared__ float wr[64 * 64];
    int tid = threadIdx.x;
    for (int t = tid; t < 4096; t += 256) { wl[t] = Wl[t]; wr[t] = Wr[t]; }
    __syncthreads();
    int r = blockIdx.x * 4 + (tid >> 6);
    int c = tid & 63;
    float av = att[c];
    const float* arow = A + r * 64;
    float accl = 0.f, accr = 0.f;
    #pragma unroll
    for (int p = 0; p < 64; ++p) {
        float a = arow[p];
        accl = fmaf(a, wl[p * 64 + c], accl);
        accr = fmaf(a, wr[p * 64 + c], accr);
    }
    xl[r * 64 + c] = accl;
    xr[r * 64 + c] = accr;
    float t = dpp_rowsum16(accl * av);
    if ((c & 15) == 15) alE[(r << 2) | (c >> 4)] = 0.6f * LOG2E * t;
}

// --- Kernel 3: fused flash GATv2, quad-cooperative loads -----------------
// ONE i-row per block (grid = B*N). Rationale (rounds 2-3 post-mortem):
// xl is L2-resident (512KB), so multi-row amortization buys ~nothing, but
// its register state (>190 live) forced wholesale spilling at the 128-VGPR
// allocation the backend insists on (189MB/dispatch scratch writes, 143us).
// 1-row live state ~110 floats < 128 -> spill-free at 4 waves/SIMD.
// lane = 4*jl + h; quad (jl) shares row j = wave*256 + jl*16 + s.
// Lane owns p-set {q*16 + 4h + r} (4 elems of each head-slice q).
// e'[j,q] = quadsum(sum_r at'[q][r]*|xr+xv|) + arE[i][q] + alE[j][q]
// with at' = 0.4*log2e*att (permuted), arE = 1.5*quadsum(at'.xr).
template <bool RELU>
__global__ __launch_bounds__(256, 4) void k_attn(
    const float* __restrict__ xl, const float* __restrict__ xr,
    const float* __restrict__ att, const float* __restrict__ alE,
    const float* __restrict__ bias, const unsigned char* __restrict__ mask,
    float* __restrict__ out)
{
    __shared__ float Opart[4][4][64];    // [wave][jlgrp][p]
    __shared__ float Lpart[4][4][NHEAD];

    int tid = threadIdx.x;
    int wave = tid >> 6, lane = tid & 63;
    int h = lane & 3, jl = lane >> 2;
    int b = blockIdx.x >> 10;
    int i = blockIdx.x & 1023;
    int j0 = (wave << 8) + (jl << 4);

    const float* xlb = xl + (b << 16);

    // permuted persistent fragments: slot q*4+r  <->  p = q*16 + 4h + r
    float at[16], xrf[16];
    {
        const float* ap = att + (h << 2);
        const float* rr = xr + (((b << 10) + i) << 6) + (h << 2);
        #pragma unroll
        for (int q = 0; q < 4; ++q) {
            *(float4*)&at[q << 2]  = *(const float4*)(ap + (q << 4));
            *(float4*)&xrf[q << 2] = *(const float4*)(rr + (q << 4));
        }
        #pragma unroll
        for (int p = 0; p < 16; ++p) at[p] *= 0.4f * LOG2E;
    }
    // arE[i][q] for all q, in every lane (init-time quad butterfly)
    float arq[4];
    #pragma unroll
    for (int q = 0; q < 4; ++q) {
        float p0 = 0.f;
        #pragma unroll
        for (int r = 0; r < 4; ++r)
            p0 = fmaf(at[(q << 2) + r], xrf[(q << 2) + r], p0);
        arq[q] = 1.5f * quad_sum4(p0);
    }

    // pack this lane's 16 mask bytes (row i, cols j0..j0+15) into 16 bits
    unsigned mb = 0;
    {
        const unsigned* mp = (const unsigned*)(mask + i * NN + j0);
        #pragma unroll
        for (int q = 0; q < 4; ++q) {
            unsigned w = mp[q];
            mb |= ((((w >> 0) & 1) | ((w >> 7) & 2) | ((w >> 14) & 4) | ((w >> 21) & 8)) << (q << 2));
        }
    }

    float O[16], lq[4] = {};
    #pragma unroll
    for (int p = 0; p < 16; ++p) O[p] = 0.f;

    const float* xrow = xlb + (j0 << 6) + (h << 2);
    const float* alp  = alE + (b << 12) + (j0 << 2);

    #pragma unroll 2
    for (int s = 0; s < 16; ++s) {
        const float* rp = xrow + (s << 6);
        float xv[16];
        *(float4*)&xv[0]  = *(const float4*)(rp);
        *(float4*)&xv[4]  = *(const float4*)(rp + 16);
        *(float4*)&xv[8]  = *(const float4*)(rp + 32);
        *(float4*)&xv[12] = *(const float4*)(rp + 48);
        float alr[4];
        *(float4*)alr = *(const float4*)(alp + (s << 2));
        bool m = (mb >> s) & 1;

        #pragma unroll
        for (int q = 0; q < 4; ++q) {
            float p0 = 0.f;
            #pragma unroll
            for (int r = 0; r < 4; ++r) {
                float xvv = xv[(q << 2) + r];
                p0 = fmaf(at[(q << 2) + r], __builtin_fabsf(xrf[(q << 2) + r] + xvv), p0);
            }
            float e = quad_sum4(p0) + (arq[q] + alr[q]);
            float pe = m ? __builtin_amdgcn_exp2f(e) : 0.f;
            lq[q] += pe;
            #pragma unroll
            for (int r = 0; r < 4; ++r) {
                float xvv = xv[(q << 2) + r];
                O[(q << 2) + r] = fmaf(pe, xvv, O[(q << 2) + r]);
            }
        }
    }

    // reduce over the 4 jl's within each 16-lane DPP row (stride-4 lanes)
    #pragma unroll
    for (int p = 0; p < 16; ++p) {
        O[p] += dpp_mov<0x114>(O[p]);
        O[p] += dpp_mov<0x118>(O[p]);
    }
    #pragma unroll
    for (int q = 0; q < 4; ++q) {
        lq[q] += dpp_mov<0x114>(lq[q]);
        lq[q] += dpp_mov<0x118>(lq[q]);
    }

    if ((lane & 15) >= 12) {             // lanes 12..15 of each DPP row
        int k = lane >> 4;               // jl-group
        #pragma unroll
        for (int q = 0; q < 4; ++q)
            *(float4*)&Opart[wave][k][(q << 4) + (h << 2)] = *(const float4*)&O[q << 2];
        if (h == 0) {
            #pragma unroll
            for (int q = 0; q < 4; ++q)
                Lpart[wave][k][q] = lq[q];
        }
    }
    __syncthreads();

    if (tid < 64) {
        int c = tid;
        float o = 0.f, l = 0.f;
        #pragma unroll
        for (int w = 0; w < 4; ++w)
            #pragma unroll
            for (int k = 0; k < 4; ++k) {
                o += Opart[w][k][c];
                l += Lpart[w][k][c >> 4];
            }
        float res = o / l + bias[c];
        if (RELU) res = fmaxf(res, 0.f);
        out[((b << 10) + i) * D + c] = res;
    }
}

extern "C" void kernel_launch(void* const* d_in, const int* in_sizes, int n_in,
                              void* d_out, int out_size, void* d_ws, size_t ws_size,
                              hipStream_t stream) {
    const float* x    = (const float*)d_in[0];
    const float* emb  = (const float*)d_in[1];
    const float* Wl1  = (const float*)d_in[2];
    const float* Wr1  = (const float*)d_in[3];
    const float* att1 = (const float*)d_in[4];
    const float* b1   = (const float*)d_in[5];
    const float* Wl2  = (const float*)d_in[6];
    const float* Wr2  = (const float*)d_in[7];
    const float* att2 = (const float*)d_in[8];
    const float* b2   = (const float*)d_in[9];
    float* out = (float*)d_out;

    unsigned char* mask = (unsigned char*)d_ws;                 // 1MB
    float* xl = (float*)(mask + NN * NN);                       // 512KB
    float* xr = xl + BB * NN * D;                               // 512KB
    float* hbuf = xr + BB * NN * D;                             // 512KB
    float* alE = hbuf + BB * NN * D;                            // 32KB

    k_mask<<<256, 256, 0, stream>>>(emb, mask);

    k_gemm2<<<BB * NN / 4, 256, 0, stream>>>(x, Wl1, Wr1, att1, xl, xr, alE);
    k_attn<true><<<BB * NN, 256, 0, stream>>>(xl, xr, att1, alE, b1, mask, hbuf);

    k_gemm2<<<BB * NN / 4, 256, 0, stream>>>(hbuf, Wl2, Wr2, att2, xl, xr, alE);
    k_attn<false><<<BB * NN, 256, 0, stream>>>(xl, xr, att2, alE, b2, mask, out);
}

// Round 5
// 132.087 us; speedup vs baseline: 2.7174x; 1.3293x over previous
//
#include <hip/hip_runtime.h>
#include <math.h>

#define NN 1024
#define BB 2
#define D 64
#define NHEAD 4
#define PH 16
#define LOG2E 1.4426950408889634f

template <int CTRL>
__device__ __forceinline__ float dpp_mov(float x) {
    int xi = __builtin_bit_cast(int, x);
    int r = __builtin_amdgcn_update_dpp(0, xi, CTRL, 0xF, 0xF, true);
    return __builtin_bit_cast(float, r);
}

// 16-lane row sum; valid in lane 15 of each row of 16.
__device__ __forceinline__ float dpp_rowsum16(float t) {
    t += dpp_mov<0x111>(t);
    t += dpp_mov<0x112>(t);
    t += dpp_mov<0x114>(t);
    t += dpp_mov<0x118>(t);
    return t;
}

// sum across a 4-lane quad via quad_perm butterfly; valid in ALL quad lanes.
__device__ __forceinline__ float quad_sum4(float t) {
    t += dpp_mov<0xB1>(t);   // quad_perm [1,0,3,2]
    t += dpp_mov<0x4E>(t);   // quad_perm [2,3,0,1]
    return t;
}

// --- Kernel 1: adjacency mask as tiled GEMM on RAW embedding rows --------
// norms are positive & finite, so (ne_i.ne_j != 0) <=> (emb_i.emb_j != 0).
#define MST 65
__global__ __launch_bounds__(256) void k_mask(const float* __restrict__ emb,
                                              unsigned char* __restrict__ mask) {
    __shared__ float As[64 * MST];
    __shared__ float Bs[64 * MST];
    int tid = threadIdx.x;
    int ib = (blockIdx.x & 15) << 6;
    int jb = (blockIdx.x >> 4) << 6;

    #pragma unroll
    for (int r = 0; r < 4; ++r) {
        int q = tid + (r << 8);
        int row = q >> 4, c4 = (q & 15) << 2;
        float4 a = *(const float4*)&emb[(ib + row) * D + c4];
        float4 b = *(const float4*)&emb[(jb + row) * D + c4];
        As[row * MST + c4 + 0] = a.x; As[row * MST + c4 + 1] = a.y;
        As[row * MST + c4 + 2] = a.z; As[row * MST + c4 + 3] = a.w;
        Bs[row * MST + c4 + 0] = b.x; Bs[row * MST + c4 + 1] = b.y;
        Bs[row * MST + c4 + 2] = b.z; Bs[row * MST + c4 + 3] = b.w;
    }
    __syncthreads();

    int i0 = (tid >> 4) << 2;
    int j0 = (tid & 15) << 2;
    float acc[4][4] = {};
    #pragma unroll 8
    for (int k = 0; k < 64; ++k) {
        float a0 = As[(i0 + 0) * MST + k];
        float a1 = As[(i0 + 1) * MST + k];
        float a2 = As[(i0 + 2) * MST + k];
        float a3 = As[(i0 + 3) * MST + k];
        float b0 = Bs[(j0 + 0) * MST + k];
        float b1 = Bs[(j0 + 1) * MST + k];
        float b2 = Bs[(j0 + 2) * MST + k];
        float b3 = Bs[(j0 + 3) * MST + k];
        acc[0][0] = fmaf(a0, b0, acc[0][0]); acc[0][1] = fmaf(a0, b1, acc[0][1]);
        acc[0][2] = fmaf(a0, b2, acc[0][2]); acc[0][3] = fmaf(a0, b3, acc[0][3]);
        acc[1][0] = fmaf(a1, b0, acc[1][0]); acc[1][1] = fmaf(a1, b1, acc[1][1]);
        acc[1][2] = fmaf(a1, b2, acc[1][2]); acc[1][3] = fmaf(a1, b3, acc[1][3]);
        acc[2][0] = fmaf(a2, b0, acc[2][0]); acc[2][1] = fmaf(a2, b1, acc[2][1]);
        acc[2][2] = fmaf(a2, b2, acc[2][2]); acc[2][3] = fmaf(a2, b3, acc[2][3]);
        acc[3][0] = fmaf(a3, b0, acc[3][0]); acc[3][1] = fmaf(a3, b1, acc[3][1]);
        acc[3][2] = fmaf(a3, b2, acc[3][2]); acc[3][3] = fmaf(a3, b3, acc[3][3]);
    }
    #pragma unroll
    for (int r = 0; r < 4; ++r) {
        int gi = ib + i0 + r;
        uchar4 m;
        m.x = (acc[r][0] != 0.f || gi == jb + j0 + 0) ? 1 : 0;
        m.y = (acc[r][1] != 0.f || gi == jb + j0 + 1) ? 1 : 0;
        m.z = (acc[r][2] != 0.f || gi == jb + j0 + 2) ? 1 : 0;
        m.w = (acc[r][3] != 0.f || gi == jb + j0 + 3) ? 1 : 0;
        *(uchar4*)&mask[gi * NN + jb + j0] = m;
    }
}

// --- Kernel 2: dual GEMM + alE tail --------------------------------------
// xl = A@Wl, xr = A@Wr; alE[r][h] = 0.6*log2(e)*sum_p att[h,p]*xl[r,h,p]
__global__ __launch_bounds__(256) void k_gemm2(const float* __restrict__ A,
                                               const float* __restrict__ Wl,
                                               const float* __restrict__ Wr,
                                               const float* __restrict__ att,
                                               float* __restrict__ xl,
                                               float* __restrict__ xr,
                                               float* __restrict__ alE) {
    __shared__ float wl[64 * 64];
    __shared__ float wr[64 * 64];
    int tid = threadIdx.x;
    for (int t = tid; t < 4096; t += 256) { wl[t] = Wl[t]; wr[t] = Wr[t]; }
    __syncthreads();
    int r = blockIdx.x * 4 + (tid >> 6);
    int c = tid & 63;
    float av = att[c];
    const float* arow = A + r * 64;
    float accl = 0.f, accr = 0.f;
    #pragma unroll
    for (int p = 0; p < 64; ++p) {
        float a = arow[p];
        accl = fmaf(a, wl[p * 64 + c], accl);
        accr = fmaf(a, wr[p * 64 + c], accr);
    }
    xl[r * 64 + c] = accl;
    xr[r * 64 + c] = accr;
    float t = dpp_rowsum16(accl * av);
    if ((c & 15) == 15) alE[(r << 2) | (c >> 4)] = 0.6f * LOG2E * t;
}

// --- Kernel 3: fused flash GATv2, quad-cooperative loads -----------------
// FOUR i-rows per block (grid = B*N/4 = 512 = 2 blocks/CU exactly).
// Round-4 showed 1-row is latency-bound (VALUBusy 35%, VGPR 52): the xv
// load stream gates everything, so amortize each load over 4 rows (4x
// fewer loads/row, 4-way compute ILP per load). Rounds 2-3 post-mortem:
// [4][16] (256B) aggregates defeat SROA -> scratch; 16-float (64B) named
// arrays always promote (rounds 0 & 4). So all per-row state is SEPARATE
// NAMED 16-float arrays. (256,2): VGPR cap 256, live ~230.
// lane = 4*jl + h; quad (jl) shares row j = wave*256 + jl*16 + s.
// Lane owns p-set {q*16 + 4h + r} (4 elems of each head-slice q).
// e'[j,q] = quadsum(sum_r at'[q][r]*|xr+xv|) + arE[i][q] + alE[j][q]
// with at' = 0.4*log2e*att (permuted), arE = 1.5*quadsum(at'.xr).
template <bool RELU>
__global__ __launch_bounds__(256, 2) void k_attn(
    const float* __restrict__ xl, const float* __restrict__ xr,
    const float* __restrict__ att, const float* __restrict__ alE,
    const float* __restrict__ bias, const unsigned char* __restrict__ mask,
    float* __restrict__ out)
{
    __shared__ float Opart[4][4][4][64];   // [ii][wave][jlgrp][p]
    __shared__ float Lpart[4][4][4][NHEAD];

    int tid = threadIdx.x;
    int wave = tid >> 6, lane = tid & 63;
    int h = lane & 3, jl = lane >> 2;
    int b = blockIdx.x >> 8;
    int i0 = (blockIdx.x & 255) << 2;
    int j0 = (wave << 8) + (jl << 4);

    const float* xlb = xl + (b << 16);

    // permuted persistent fragments: slot q*4+r  <->  p = q*16 + 4h + r
    float at[16], xr0f[16], xr1f[16], xr2f[16], xr3f[16];
    {
        const float* ap = att + (h << 2);
        const float* r0 = xr + (((b << 10) + i0) << 6) + (h << 2);
        const float* r1 = r0 + 64;
        const float* r2 = r0 + 128;
        const float* r3 = r0 + 192;
        #pragma unroll
        for (int q = 0; q < 4; ++q) {
            *(float4*)&at[q << 2]   = *(const float4*)(ap + (q << 4));
            *(float4*)&xr0f[q << 2] = *(const float4*)(r0 + (q << 4));
            *(float4*)&xr1f[q << 2] = *(const float4*)(r1 + (q << 4));
            *(float4*)&xr2f[q << 2] = *(const float4*)(r2 + (q << 4));
            *(float4*)&xr3f[q << 2] = *(const float4*)(r3 + (q << 4));
        }
        #pragma unroll
        for (int p = 0; p < 16; ++p) at[p] *= 0.4f * LOG2E;
    }
    // arE[i][q] for all q, in every lane (init-time quad butterfly)
    float ar0q[4], ar1q[4], ar2q[4], ar3q[4];
    #pragma unroll
    for (int q = 0; q < 4; ++q) {
        float p0 = 0.f, p1 = 0.f, p2 = 0.f, p3 = 0.f;
        #pragma unroll
        for (int r = 0; r < 4; ++r) {
            float a = at[(q << 2) + r];
            p0 = fmaf(a, xr0f[(q << 2) + r], p0);
            p1 = fmaf(a, xr1f[(q << 2) + r], p1);
            p2 = fmaf(a, xr2f[(q << 2) + r], p2);
            p3 = fmaf(a, xr3f[(q << 2) + r], p3);
        }
        ar0q[q] = 1.5f * quad_sum4(p0);
        ar1q[q] = 1.5f * quad_sum4(p1);
        ar2q[q] = 1.5f * quad_sum4(p2);
        ar3q[q] = 1.5f * quad_sum4(p3);
    }

    // pack this lane's 16 mask bytes into 16 bits, rows i0..i0+3
    unsigned mb0 = 0, mb1 = 0, mb2 = 0, mb3 = 0;
    {
        const unsigned* m0p = (const unsigned*)(mask + (i0 + 0) * NN + j0);
        const unsigned* m1p = (const unsigned*)(mask + (i0 + 1) * NN + j0);
        const unsigned* m2p = (const unsigned*)(mask + (i0 + 2) * NN + j0);
        const unsigned* m3p = (const unsigned*)(mask + (i0 + 3) * NN + j0);
        #pragma unroll
        for (int q = 0; q < 4; ++q) {
            unsigned w0 = m0p[q], w1 = m1p[q], w2 = m2p[q], w3 = m3p[q];
            mb0 |= ((((w0 >> 0) & 1) | ((w0 >> 7) & 2) | ((w0 >> 14) & 4) | ((w0 >> 21) & 8)) << (q << 2));
            mb1 |= ((((w1 >> 0) & 1) | ((w1 >> 7) & 2) | ((w1 >> 14) & 4) | ((w1 >> 21) & 8)) << (q << 2));
            mb2 |= ((((w2 >> 0) & 1) | ((w2 >> 7) & 2) | ((w2 >> 14) & 4) | ((w2 >> 21) & 8)) << (q << 2));
            mb3 |= ((((w3 >> 0) & 1) | ((w3 >> 7) & 2) | ((w3 >> 14) & 4) | ((w3 >> 21) & 8)) << (q << 2));
        }
    }

    float O0[16], O1[16], O2[16], O3[16];
    float l0q[4] = {}, l1q[4] = {}, l2q[4] = {}, l3q[4] = {};
    #pragma unroll
    for (int p = 0; p < 16; ++p) { O0[p] = 0.f; O1[p] = 0.f; O2[p] = 0.f; O3[p] = 0.f; }

    const float* xrow = xlb + (j0 << 6) + (h << 2);
    const float* alp  = alE + (b << 12) + (j0 << 2);

    #pragma unroll 2
    for (int s = 0; s < 16; ++s) {
        const float* rp = xrow + (s << 6);
        float xv[16];
        *(float4*)&xv[0]  = *(const float4*)(rp);
        *(float4*)&xv[4]  = *(const float4*)(rp + 16);
        *(float4*)&xv[8]  = *(const float4*)(rp + 32);
        *(float4*)&xv[12] = *(const float4*)(rp + 48);
        float alr[4];
        *(float4*)alr = *(const float4*)(alp + (s << 2));
        bool m0 = (mb0 >> s) & 1, m1 = (mb1 >> s) & 1;
        bool m2 = (mb2 >> s) & 1, m3 = (mb3 >> s) & 1;

        #pragma unroll
        for (int q = 0; q < 4; ++q) {
            float p0 = 0.f, p1 = 0.f, p2 = 0.f, p3 = 0.f;
            #pragma unroll
            for (int r = 0; r < 4; ++r) {
                float xvv = xv[(q << 2) + r];
                float a = at[(q << 2) + r];
                p0 = fmaf(a, __builtin_fabsf(xr0f[(q << 2) + r] + xvv), p0);
                p1 = fmaf(a, __builtin_fabsf(xr1f[(q << 2) + r] + xvv), p1);
                p2 = fmaf(a, __builtin_fabsf(xr2f[(q << 2) + r] + xvv), p2);
                p3 = fmaf(a, __builtin_fabsf(xr3f[(q << 2) + r] + xvv), p3);
            }
            float e0 = quad_sum4(p0) + (ar0q[q] + alr[q]);
            float e1 = quad_sum4(p1) + (ar1q[q] + alr[q]);
            float e2 = quad_sum4(p2) + (ar2q[q] + alr[q]);
            float e3 = quad_sum4(p3) + (ar3q[q] + alr[q]);
            float pe0 = m0 ? __builtin_amdgcn_exp2f(e0) : 0.f;
            float pe1 = m1 ? __builtin_amdgcn_exp2f(e1) : 0.f;
            float pe2 = m2 ? __builtin_amdgcn_exp2f(e2) : 0.f;
            float pe3 = m3 ? __builtin_amdgcn_exp2f(e3) : 0.f;
            l0q[q] += pe0; l1q[q] += pe1; l2q[q] += pe2; l3q[q] += pe3;
            #pragma unroll
            for (int r = 0; r < 4; ++r) {
                float xvv = xv[(q << 2) + r];
                O0[(q << 2) + r] = fmaf(pe0, xvv, O0[(q << 2) + r]);
                O1[(q << 2) + r] = fmaf(pe1, xvv, O1[(q << 2) + r]);
                O2[(q << 2) + r] = fmaf(pe2, xvv, O2[(q << 2) + r]);
                O3[(q << 2) + r] = fmaf(pe3, xvv, O3[(q << 2) + r]);
            }
        }
    }

    // reduce over the 4 jl's within each 16-lane DPP row (stride-4 lanes)
    #pragma unroll
    for (int p = 0; p < 16; ++p) {
        O0[p] += dpp_mov<0x114>(O0[p]);  O0[p] += dpp_mov<0x118>(O0[p]);
        O1[p] += dpp_mov<0x114>(O1[p]);  O1[p] += dpp_mov<0x118>(O1[p]);
        O2[p] += dpp_mov<0x114>(O2[p]);  O2[p] += dpp_mov<0x118>(O2[p]);
        O3[p] += dpp_mov<0x114>(O3[p]);  O3[p] += dpp_mov<0x118>(O3[p]);
    }
    #pragma unroll
    for (int q = 0; q < 4; ++q) {
        l0q[q] += dpp_mov<0x114>(l0q[q]);  l0q[q] += dpp_mov<0x118>(l0q[q]);
        l1q[q] += dpp_mov<0x114>(l1q[q]);  l1q[q] += dpp_mov<0x118>(l1q[q]);
        l2q[q] += dpp_mov<0x114>(l2q[q]);  l2q[q] += dpp_mov<0x118>(l2q[q]);
        l3q[q] += dpp_mov<0x114>(l3q[q]);  l3q[q] += dpp_mov<0x118>(l3q[q]);
    }

    if ((lane & 15) >= 12) {             // lanes 12..15 of each DPP row
        int k = lane >> 4;               // jl-group
        #pragma unroll
        for (int q = 0; q < 4; ++q) {
            *(float4*)&Opart[0][wave][k][(q << 4) + (h << 2)] = *(const float4*)&O0[q << 2];
            *(float4*)&Opart[1][wave][k][(q << 4) + (h << 2)] = *(const float4*)&O1[q << 2];
            *(float4*)&Opart[2][wave][k][(q << 4) + (h << 2)] = *(const float4*)&O2[q << 2];
            *(float4*)&Opart[3][wave][k][(q << 4) + (h << 2)] = *(const float4*)&O3[q << 2];
        }
        if (h == 0) {
            #pragma unroll
            for (int q = 0; q < 4; ++q) {
                Lpart[0][wave][k][q] = l0q[q];
                Lpart[1][wave][k][q] = l1q[q];
                Lpart[2][wave][k][q] = l2q[q];
                Lpart[3][wave][k][q] = l3q[q];
            }
        }
    }
    __syncthreads();

    {
        int ii = tid >> 6, c = tid & 63;
        float o = 0.f, l = 0.f;
        #pragma unroll
        for (int w = 0; w < 4; ++w)
            #pragma unroll
            for (int k = 0; k < 4; ++k) {
                o += Opart[ii][w][k][c];
                l += Lpart[ii][w][k][c >> 4];
            }
        float res = o / l + bias[c];
        if (RELU) res = fmaxf(res, 0.f);
        out[((b << 10) + i0 + ii) * D + c] = res;
    }
}

extern "C" void kernel_launch(void* const* d_in, const int* in_sizes, int n_in,
                              void* d_out, int out_size, void* d_ws, size_t ws_size,
                              hipStream_t stream) {
    const float* x    = (const float*)d_in[0];
    const float* emb  = (const float*)d_in[1];
    const float* Wl1  = (const float*)d_in[2];
    const float* Wr1  = (const float*)d_in[3];
    const float* att1 = (const float*)d_in[4];
    const float* b1   = (const float*)d_in[5];
    const float* Wl2  = (const float*)d_in[6];
    const float* Wr2  = (const float*)d_in[7];
    const float* att2 = (const float*)d_in[8];
    const float* b2   = (const float*)d_in[9];
    float* out = (float*)d_out;

    unsigned char* mask = (unsigned char*)d_ws;                 // 1MB
    float* xl = (float*)(mask + NN * NN);                       // 512KB
    float* xr = xl + BB * NN * D;                               // 512KB
    float* hbuf = xr + BB * NN * D;                             // 512KB
    float* alE = hbuf + BB * NN * D;                            // 32KB

    k_mask<<<256, 256, 0, stream>>>(emb, mask);

    k_gemm2<<<BB * NN / 4, 256, 0, stream>>>(x, Wl1, Wr1, att1, xl, xr, alE);
    k_attn<true><<<BB * NN / 4, 256, 0, stream>>>(xl, xr, att1, alE, b1, mask, hbuf);

    k_gemm2<<<BB * NN / 4, 256, 0, stream>>>(hbuf, Wl2, Wr2, att2, xl, xr, alE);
    k_attn<false><<<BB * NN / 4, 256, 0, stream>>>(xl, xr, att2, alE, b2, mask, out);
}